// Round 1
// baseline (28799.185 us; speedup 1.0000x reference)
//
#include <hip/hip_runtime.h>

#define B   32
#define L   64
#define DH  1024
#define G4  4096
#define EK  512
#define V   32000

__device__ __forceinline__ float sigm(float x){ return 1.f/(1.f+expf(-x)); }
__device__ __forceinline__ unsigned mono(float f){
  unsigned u = __float_as_uint(f);
  return (u & 0x80000000u) ? ~u : (u | 0x80000000u);
}

// zero h and c (32x1024 each)
__global__ __launch_bounds__(256) void init_kernel(float* h, float* c){
  int i = blockIdx.x*256 + threadIdx.x;
  if (i < B*DH){ h[i]=0.f; c[i]=0.f; }
}

// Fused LSTM-gates + cell update. mode 0: encoder (x1 = embed gather, K1=512)
// mode 1: decoder (x1 = relu(inp), K1=1024). Always x2 = h_in (K=1024).
// grid 128 blocks x 256 thr; block covers 8 hidden cols x 4 gates x 32 rows.
__global__ __launch_bounds__(256) void gates_kernel(
    int mode, int t,
    const int* __restrict__ x, const float* __restrict__ embed,
    const float* __restrict__ src1, int K1,
    const float* __restrict__ wx, const float* __restrict__ wh,
    const float* __restrict__ bias,
    const float* __restrict__ h_in, float* __restrict__ h_out,
    float* __restrict__ cst, float* __restrict__ enc_outs)
{
  __shared__ float es[128][36];
  __shared__ int tok_s[B];
  __shared__ float gate_s[4][8][B];
  int tid = threadIdx.x;
  int hc = tid & 7, g = (tid>>3)&3, rg = tid>>5;
  int jh = blockIdx.x*8 + hc;
  int jg = g*DH + jh;
  float a0=0.f,a1=0.f,a2=0.f,a3=0.f;
  if (mode==0 && tid < B) tok_s[tid] = x[tid*L + t];
  __syncthreads();
  for (int phase=0; phase<2; ++phase){
    int K = phase ? DH : K1;
    const float* W = phase ? wh : wx;
    for (int kb=0; kb<K; kb+=128){
      for (int i=0;i<16;++i){
        int idx = i*256 + tid;
        int b = idx >> 7, kk = idx & 127;
        int k = kb + kk;
        float v;
        if (phase)          v = h_in[b*DH + k];
        else if (mode==0)   v = embed[(long)tok_s[b]*EK + k];
        else { v = src1[b*DH + k]; v = v>0.f ? v : 0.f; }
        es[kk][b] = v;
      }
      __syncthreads();
      #pragma unroll 8
      for (int kk=0; kk<128; ++kk){
        float w = W[(long)(kb+kk)*G4 + jg];
        float4 hv = *reinterpret_cast<const float4*>(&es[kk][rg*4]);
        a0 += hv.x*w; a1 += hv.y*w; a2 += hv.z*w; a3 += hv.w*w;
      }
      __syncthreads();
    }
  }
  float bj = bias[jg];
  gate_s[g][hc][rg*4+0] = a0+bj;
  gate_s[g][hc][rg*4+1] = a1+bj;
  gate_s[g][hc][rg*4+2] = a2+bj;
  gate_s[g][hc][rg*4+3] = a3+bj;
  __syncthreads();
  if (tid < 64){
    int hc2 = tid & 7, rg2 = tid >> 3;
    int j = blockIdx.x*8 + hc2;
    for (int i=0;i<4;++i){
      int b = rg2*4 + i;
      float iv = gate_s[0][hc2][b];
      float fv = gate_s[1][hc2][b];
      float gv = gate_s[2][hc2][b];
      float ov = gate_s[3][hc2][b];
      float cn = sigm(fv)*cst[b*DH + j] + sigm(iv)*tanhf(gv);
      cst[b*DH + j] = cn;
      float hv = sigm(ov)*tanhf(cn);
      h_out[b*DH + j] = hv;
      if (enc_outs) enc_outs[((long)b*L + t)*DH + j] = hv;
    }
  }
}

// Per-step attention: tok gather -> scores -> softmax -> ctx.
// Also seeds inp = comb_b (combine bias) for the atomic-split combine GEMM.
// grid 32 blocks (one per batch row) x 256 thr.
__global__ __launch_bounds__(256) void attn_kernel(
    int t, const unsigned long long* __restrict__ ptok,
    const float* __restrict__ dec_embed, const float* __restrict__ attn_w,
    const float* __restrict__ attn_b, const float* __restrict__ h_in,
    const float* __restrict__ enc_outs,
    float* __restrict__ e_buf, float* __restrict__ ctx,
    float* __restrict__ inp, const float* __restrict__ comb_b)
{
  __shared__ float e_s[DH], h_s[DH], sc_s[4][64], aw_s[64];
  __shared__ int tok_sh;
  int b = blockIdx.x, tid = threadIdx.x;
  if (tid==0){
    int tok = 127;
    if (t > 0) tok = (int)(~(unsigned)(ptok[(t-1)*B + b] & 0xffffffffull));
    tok_sh = tok;
  }
  __syncthreads();
  int tok = tok_sh;
  for (int i=0;i<4;++i){
    int k = i*256 + tid;
    float ev = dec_embed[(long)tok*DH + k];
    float hv = h_in[b*DH + k];
    e_s[k]=ev; h_s[k]=hv;
    e_buf[b*DH + k] = ev;
    inp[b*DH + k] = comb_b[k];
  }
  __syncthreads();
  int l = tid & 63, ks = tid >> 6;
  float p = 0.f;
  for (int kk=0; kk<512; ++kk){
    int k = ks*512 + kk;
    float sv = (k < DH) ? e_s[k] : h_s[k-DH];
    p += sv * attn_w[(long)k*64 + l];
  }
  sc_s[ks][l] = p;
  __syncthreads();
  if (tid < 64){
    float s = sc_s[0][l]+sc_s[1][l]+sc_s[2][l]+sc_s[3][l] + attn_b[l];
    float m = s;
    for (int off=32; off; off>>=1) m = fmaxf(m, __shfl_xor(m, off));
    float e = expf(s-m);
    float sum = e;
    for (int off=32; off; off>>=1) sum += __shfl_xor(sum, off);
    aw_s[l] = e/sum;
  }
  __syncthreads();
  float c0=0.f,c1=0.f,c2=0.f,c3=0.f;
  for (int ll=0; ll<64; ++ll){
    float a = aw_s[ll];
    const float* er = &enc_outs[((long)b*L + ll)*DH];
    c0 += a*er[tid]; c1 += a*er[256+tid]; c2 += a*er[512+tid]; c3 += a*er[768+tid];
  }
  ctx[b*DH + tid]       = c0;
  ctx[b*DH + 256 + tid] = c1;
  ctx[b*DH + 512 + tid] = c2;
  ctx[b*DH + 768 + tid] = c3;
}

// Combine GEMM, K-split x4 with atomic accumulate into inp (pre-seeded with bias).
// grid (32 colblocks, 4 ksplit) x 256 thr.
__global__ __launch_bounds__(256) void comb_kernel(
    const float* __restrict__ e_buf, const float* __restrict__ ctx,
    const float* __restrict__ comb_w, float* __restrict__ inp)
{
  __shared__ float es[128][36];
  int tid = threadIdx.x;
  int col = tid & 31, rg = tid >> 5;
  int j = blockIdx.x*32 + col;
  int kr = blockIdx.y;
  const float* src = (kr < 2) ? e_buf : ctx;
  int kbase0 = (kr & 1)*512;
  float a0=0.f,a1=0.f,a2=0.f,a3=0.f;
  for (int kb=0; kb<512; kb+=128){
    for (int i=0;i<16;++i){
      int idx = i*256 + tid;
      int b = idx >> 7, kk = idx & 127;
      es[kk][b] = src[b*DH + kbase0 + kb + kk];
    }
    __syncthreads();
    #pragma unroll 8
    for (int kk=0; kk<128; ++kk){
      float w = comb_w[(long)(kr*512 + kb + kk)*DH + j];
      float4 hv = *reinterpret_cast<const float4*>(&es[kk][rg*4]);
      a0 += hv.x*w; a1 += hv.y*w; a2 += hv.z*w; a3 += hv.w*w;
    }
    __syncthreads();
  }
  atomicAdd(&inp[(rg*4+0)*DH + j], a0);
  atomicAdd(&inp[(rg*4+1)*DH + j], a1);
  atomicAdd(&inp[(rg*4+2)*DH + j], a2);
  atomicAdd(&inp[(rg*4+3)*DH + j], a3);
}

// Output projection: raw logits -> d_out, per-block partial sumexp + packed argmax.
// grid 1000 blocks x 256 thr (32 cols x 8 rowgroups of 4).
__global__ __launch_bounds__(256) void outproj_kernel(
    int t, const float* __restrict__ hsrc, const float* __restrict__ out_w,
    const float* __restrict__ out_b, float* __restrict__ out,
    float* __restrict__ psum, unsigned long long* __restrict__ pmax)
{
  __shared__ float hs[128][36];
  __shared__ float red_s[B][33];
  __shared__ unsigned long long pk_s[B][33];
  int tid = threadIdx.x;
  int col = tid & 31, rg = tid >> 5;
  int j = blockIdx.x*32 + col;
  float a0=0.f,a1=0.f,a2=0.f,a3=0.f;
  for (int kb=0; kb<DH; kb+=128){
    for (int i=0;i<16;++i){
      int idx = i*256 + tid;
      int b = idx >> 7, kk = idx & 127;
      hs[kk][b] = hsrc[b*DH + kb + kk];
    }
    __syncthreads();
    #pragma unroll 8
    for (int kk=0; kk<128; ++kk){
      float w = out_w[(long)(kb+kk)*V + j];
      float4 hv = *reinterpret_cast<const float4*>(&hs[kk][rg*4]);
      a0 += hv.x*w; a1 += hv.y*w; a2 += hv.z*w; a3 += hv.w*w;
    }
    __syncthreads();
  }
  float bj = out_b[j];
  float lg0=a0+bj, lg1=a1+bj, lg2=a2+bj, lg3=a3+bj;
  int r0 = rg*4;
  out[((long)(r0+0)*L + t)*V + j] = lg0;
  out[((long)(r0+1)*L + t)*V + j] = lg1;
  out[((long)(r0+2)*L + t)*V + j] = lg2;
  out[((long)(r0+3)*L + t)*V + j] = lg3;
  unsigned nj = ~(unsigned)j;
  red_s[r0+0][col] = expf(lg0);
  red_s[r0+1][col] = expf(lg1);
  red_s[r0+2][col] = expf(lg2);
  red_s[r0+3][col] = expf(lg3);
  pk_s[r0+0][col] = ((unsigned long long)mono(lg0)<<32) | nj;
  pk_s[r0+1][col] = ((unsigned long long)mono(lg1)<<32) | nj;
  pk_s[r0+2][col] = ((unsigned long long)mono(lg2)<<32) | nj;
  pk_s[r0+3][col] = ((unsigned long long)mono(lg3)<<32) | nj;
  __syncthreads();
  if (tid < B){
    float s = 0.f; unsigned long long mx = 0ull;
    for (int cc=0; cc<32; ++cc){
      s += red_s[tid][cc];
      unsigned long long v = pk_s[tid][cc];
      if (v > mx) mx = v;
    }
    psum[tid*1024 + blockIdx.x] = s;
    pmax[tid*1024 + blockIdx.x] = mx;
  }
}

// Final per-row reduce over 1000 block partials -> lse[t][b], packed tok[t][b].
__global__ __launch_bounds__(256) void reduce_kernel(
    int t, const float* __restrict__ psum, const unsigned long long* __restrict__ pmax,
    float* __restrict__ lse, unsigned long long* __restrict__ ptok)
{
  __shared__ float ss[256];
  __shared__ unsigned long long ms[256];
  int row = blockIdx.x, tid = threadIdx.x;
  float s = 0.f; unsigned long long mx = 0ull;
  for (int i=tid; i<1000; i+=256){
    s += psum[row*1024 + i];
    unsigned long long v = pmax[row*1024 + i];
    if (v > mx) mx = v;
  }
  ss[tid]=s; ms[tid]=mx;
  __syncthreads();
  for (int off=128; off; off>>=1){
    if (tid < off){
      ss[tid] += ss[tid+off];
      if (ms[tid+off] > ms[tid]) ms[tid] = ms[tid+off];
    }
    __syncthreads();
  }
  if (tid==0){
    lse[t*B + row] = logf(ss[0]);
    ptok[t*B + row] = ms[0];
  }
}

// logp = logits - lse, in place on d_out. grid (125, 32) x 256.
__global__ __launch_bounds__(256) void norm_kernel(
    int t, float* __restrict__ out, const float* __restrict__ lse)
{
  int v = blockIdx.x*256 + threadIdx.x;
  int b = blockIdx.y;
  out[((long)b*L + t)*V + v] -= lse[t*B + b];
}

extern "C" void kernel_launch(void* const* d_in, const int* in_sizes, int n_in,
                              void* d_out, int out_size, void* d_ws, size_t ws_size,
                              hipStream_t stream)
{
  const int*   x         = (const int*)  d_in[0];
  const float* enc_embed = (const float*)d_in[1];
  const float* enc_wx    = (const float*)d_in[2];
  const float* enc_wh    = (const float*)d_in[3];
  const float* enc_b     = (const float*)d_in[4];
  const float* dec_embed = (const float*)d_in[5];
  const float* attn_w    = (const float*)d_in[6];
  const float* attn_b    = (const float*)d_in[7];
  const float* comb_w    = (const float*)d_in[8];
  const float* comb_b    = (const float*)d_in[9];
  const float* dec_wx    = (const float*)d_in[10];
  const float* dec_wh    = (const float*)d_in[11];
  const float* dec_b     = (const float*)d_in[12];
  const float* out_w     = (const float*)d_in[13];
  const float* out_b     = (const float*)d_in[14];
  float* out = (float*)d_out;

  float* enc_outs = (float*)d_ws;                 // 32*64*1024
  float* h0    = enc_outs + (size_t)B*L*DH;       // 32*1024
  float* h1    = h0 + B*DH;
  float* c     = h1 + B*DH;
  float* e_buf = c  + B*DH;
  float* ctx   = e_buf + B*DH;
  float* inp   = ctx + B*DH;
  float* psum  = inp + B*DH;                      // 32*1024
  float* lse   = psum + B*1024;                   // 64*32
  unsigned long long* pmax = (unsigned long long*)(lse + L*B);  // 32*1024
  unsigned long long* ptok = pmax + B*1024;       // 64*32

  init_kernel<<<128,256,0,stream>>>(h0, c);
  for (int t=0; t<L; ++t){
    const float* hi = (t&1) ? h1 : h0;
    float*       ho = (t&1) ? h0 : h1;
    gates_kernel<<<128,256,0,stream>>>(0, t, x, enc_embed, nullptr, EK,
        enc_wx, enc_wh, enc_b, hi, ho, c, enc_outs);
  }
  init_kernel<<<128,256,0,stream>>>(h0, c);
  for (int t=0; t<L; ++t){
    const float* hi = (t&1) ? h1 : h0;
    float*       ho = (t&1) ? h0 : h1;
    attn_kernel<<<B,256,0,stream>>>(t, ptok, dec_embed, attn_w, attn_b,
        hi, enc_outs, e_buf, ctx, inp, comb_b);
    comb_kernel<<<dim3(32,4),256,0,stream>>>(e_buf, ctx, comb_w, inp);
    gates_kernel<<<128,256,0,stream>>>(1, t, nullptr, nullptr, inp, DH,
        dec_wx, dec_wh, dec_b, hi, ho, c, nullptr);
    outproj_kernel<<<1000,256,0,stream>>>(t, ho, out_w, out_b, out, psum, pmax);
    reduce_kernel<<<B,256,0,stream>>>(t, psum, pmax, lse, ptok);
    norm_kernel<<<dim3(125,B),256,0,stream>>>(t, out, lse);
  }
}